// Round 12
// baseline (195.139 us; speedup 1.0000x reference)
//
#include <hip/hip_runtime.h>
#include <math.h>

#define BDIM 4
#define DIM 512
#define TT 2048
#define CDIM 14
#define NTOK (BDIM * TT)              // 8192 tokens
#define NB 16384                      // 2^14 codes
#define OUT_ELEMS (BDIM * DIM * TT)   // 4194304
#define FEPS 1e-20f
#define PHARD 1e-6f                   // soft-bit cutoff (aux err <1e-5 vs thr 327)

// ---- fast-path ws layout (R8's WS3) ----
#define WS3_PSE_OFF  0                // 256 f32
#define WS3_COM_OFF  1024             // 256 f32
#define WS3_CNTR_OFF 2048             // 1 u32
#define WS3_H_OFF    4096             // 14*8192 f32 = 448 KB
#define WS3_HIST_OFF 462848           // 16384 f32 = 64 KB
#define WS3_NEED     528384

// ---- fallback-path ws layout (R5-proven) ----
#define WS_HIST_OFF 0
#define WS_PSE_OFF  65536
#define WS_COM_OFF  73728
#define WS_PW_OFF   81920
#define WS_NEED (81920 + 4 * 14 * 8192 * 4)

// ===========================================================================
// Node 1: k_head2 — R8-proven (~6us): GEMV + tail (idx/pse/commit) + h->ws.
// Zeroes hist + counter (safe: NO hist atomics in this kernel).
// 256 blocks x 512 thr.
// ===========================================================================
__global__ __launch_bounds__(512) void k_head2(
    const float* __restrict__ x,
    const float* __restrict__ W_in,
    const float* __restrict__ b_in,
    float* __restrict__ out_idx,
    float* __restrict__ h_ws,
    float* __restrict__ hist,
    unsigned int* __restrict__ counter,
    float* __restrict__ pse_part,
    float* __restrict__ com_part)
{
    __shared__ float Wl[DIM][16];       // 32 KB
    __shared__ float sred[8][32][15];   // 15 KB
    __shared__ float sps[8], scm[8];

    const int tid = threadIdx.x;
    const int bid = blockIdx.x;

    if (bid < 32) hist[bid * 512 + tid] = 0.f;       // zero hist
    if (bid == 32 && tid == 0) *counter = 0u;        // zero completion counter

    const int b = bid >> 6;             // 64 tiles per batch
    const int t0 = (bid & 63) * 32;

    for (int i = tid; i < DIM * CDIM; i += 512) {
        const int c = i >> 9;
        const int r = i & (DIM - 1);
        Wl[r][c] = W_in[c * DIM + r];
    }
    __syncthreads();

    const int w = tid >> 6;             // wave 0..7 -> d-rows [w*64, w*64+64)
    const int lane = tid & 63;
    const int tl = lane & 7;            // 8 t-lanes x float4 = 32 tokens
    const int dr = lane >> 3;           // 8 d-rows per instruction

    float acc[4][14];
#pragma unroll
    for (int j = 0; j < 4; ++j)
#pragma unroll
        for (int c = 0; c < 14; ++c) acc[j][c] = 0.f;

#pragma unroll
    for (int i = 0; i < 8; ++i) {
        const int r = w * 64 + i * 8 + dr;
        const float4 xv = *(const float4*)(x + (size_t)(b * DIM + r) * TT + t0 + tl * 4);
        const float4* wr = (const float4*)(&Wl[r][0]);
        const float4 w0 = wr[0];
        const float4 w1 = wr[1];
        const float4 w2 = wr[2];
        const float2 w3 = ((const float2*)wr)[6];
        const float xs[4] = {xv.x, xv.y, xv.z, xv.w};
#pragma unroll
        for (int j = 0; j < 4; ++j) {
            const float v = xs[j];
            acc[j][0]  = fmaf(v, w0.x, acc[j][0]);
            acc[j][1]  = fmaf(v, w0.y, acc[j][1]);
            acc[j][2]  = fmaf(v, w0.z, acc[j][2]);
            acc[j][3]  = fmaf(v, w0.w, acc[j][3]);
            acc[j][4]  = fmaf(v, w1.x, acc[j][4]);
            acc[j][5]  = fmaf(v, w1.y, acc[j][5]);
            acc[j][6]  = fmaf(v, w1.z, acc[j][6]);
            acc[j][7]  = fmaf(v, w1.w, acc[j][7]);
            acc[j][8]  = fmaf(v, w2.x, acc[j][8]);
            acc[j][9]  = fmaf(v, w2.y, acc[j][9]);
            acc[j][10] = fmaf(v, w2.z, acc[j][10]);
            acc[j][11] = fmaf(v, w2.w, acc[j][11]);
            acc[j][12] = fmaf(v, w3.x, acc[j][12]);
            acc[j][13] = fmaf(v, w3.y, acc[j][13]);
        }
    }

#pragma unroll
    for (int j = 0; j < 4; ++j)
#pragma unroll
        for (int c = 0; c < 14; ++c) {
            float v = acc[j][c];
            v += __shfl_xor(v, 8);
            v += __shfl_xor(v, 16);
            v += __shfl_xor(v, 32);
            acc[j][c] = v;
        }

    if (dr == 0) {
#pragma unroll
        for (int j = 0; j < 4; ++j)
#pragma unroll
            for (int c = 0; c < 14; ++c)
                sred[w][tl * 4 + j][c] = acc[j][c];
    }
    __syncthreads();

    // ---- tail: wave w handles tokens w*4..w*4+3; 16 lanes per token ----
    const int g = lane >> 4;
    const int sub = lane & 15;
    const int tk = w * 4 + g;
    const int tok = bid * 32 + tk;

    float h[14];
#pragma unroll
    for (int c = 0; c < 14; ++c) {
        float s = b_in[c];
#pragma unroll
        for (int wv = 0; wv < 8; ++wv) s += sred[wv][tk][c];
        h[c] = s;
    }

    unsigned int idx = 0;
    float pse = 0.f, commit = 0.f;
#pragma unroll
    for (int c = 0; c < 14; ++c) {
        const float hc = h[c];
        const unsigned int bit = 1u << (13 - c);
        const bool pos = hc > 0.f;
        if (pos) idx |= bit;
        const float sgn = pos ? 1.f : -1.f;
        const float dlt = hc - sgn;
        commit += dlt * dlt;
        const float pc = 1.f / (1.f + expf(-400.f * hc));  // sigmoid(400h)
        const float qc = 1.f - pc;
        pse -= pc * logf(fmaxf(pc, FEPS)) + qc * logf(fmaxf(qc, FEPS));
    }

    if (sub == 0) {
        out_idx[tok] = (float)idx;
#pragma unroll
        for (int c = 0; c < 14; ++c)
            h_ws[c * NTOK + tok] = h[c];
    }

    float pv = (sub == 0) ? pse : 0.f;
    float cv = (sub == 0) ? commit : 0.f;
#pragma unroll
    for (int o = 1; o < 64; o <<= 1) {
        pv += __shfl_xor(pv, o);
        cv += __shfl_xor(cv, o);
    }
    if (lane == 0) { sps[w] = pv; scm[w] = cv; }
    __syncthreads();
    if (tid == 0) {
        float a = 0.f, bb = 0.f;
#pragma unroll
        for (int i = 0; i < 8; ++i) { a += sps[i]; bb += scm[i]; }
        pse_part[bid] = a;
        com_part[bid] = bb;
    }
}

// ===========================================================================
// Node 2: k_mega2 — R8's k_mega with the spill FIXED via
// __launch_bounds__(256, 1): R8 compiled at VGPR_Count=24 with FETCH=2GB
// (total scratch spill, 180us); min-1-wave/EU gives the full register
// budget. Phases: coalesced proj_out (2048 elem/block), wave-per-token
// enumeration -> global hist atomics, last-block gate + finalize.
// ===========================================================================
__global__ __launch_bounds__(256, 1) void k_mega2(
    const float* __restrict__ idxf,
    const float* __restrict__ W_out,
    const float* __restrict__ b_out,
    float* __restrict__ out,
    const float* __restrict__ h_ws,
    float* __restrict__ hist,
    unsigned int* __restrict__ counter,
    const float* __restrict__ pse_part,
    const float* __restrict__ com_part,
    float* __restrict__ aux_out)
{
    const int tid = threadIdx.x;
    const int bid = blockIdx.x;

    // ---- phase 1: proj_out (coalesced; d block-uniform) ----
    {
        const int b = bid >> 9;
        const int d = bid & (DIM - 1);
        const size_t base = (size_t)bid * 2048;

        float w[14];
#pragma unroll
        for (int c = 0; c < 14; ++c) w[c] = W_out[d * 14 + c];
        const float bo = b_out[d];

#pragma unroll
        for (int half = 0; half < 2; ++half) {
            const int t = half * 1024 + tid * 4;
            const float4 uf = *(const float4*)(idxf + b * TT + t);
            const float us[4] = {uf.x, uf.y, uf.z, uf.w};
            float os[4];
#pragma unroll
            for (int j = 0; j < 4; ++j) {
                const unsigned int u = (unsigned int)us[j];
                float s = bo;
#pragma unroll
                for (int c = 0; c < 14; ++c)
                    s += (u & (1u << (13 - c))) ? w[c] : -w[c];
                os[j] = s;
            }
            float4 o; o.x = os[0]; o.y = os[1]; o.z = os[2]; o.w = os[3];
            *(float4*)(out + base + t) = o;
        }
    }

    // ---- phase 2: wave-per-token enumeration (R5 k_tail_w pattern) ----
    {
        const int wv = tid >> 6;
        const int lane = tid & 63;
        const int tok = bid * 4 + wv;

        float h[14];
#pragma unroll
        for (int c = 0; c < 14; ++c) h[c] = h_ws[c * NTOK + tok];

        unsigned int hbase = 0, softmask = 0;
        float pp[14], qq[14];
#pragma unroll
        for (int c = 0; c < 14; ++c) {
            const float hc = h[c];
            const unsigned int bit = 1u << (13 - c);
            const float pc = 1.f / (1.f + expf(-400.f * hc));
            const float qc = 1.f - pc;
            const bool hard1 = (qc <= PHARD);
            const bool hard0 = (pc <= PHARD);
            if (hard1) hbase |= bit;
            if (!hard1 && !hard0) softmask |= bit;
            pp[c] = pc;
            qq[c] = qc;
        }

        const unsigned int nsub = 1u << __popc(softmask);
        for (unsigned int m = lane; m < nsub; m += 64) {
            unsigned int rem = m, code = hbase;
            float pr = 1.f;
#pragma unroll
            for (int c = 0; c < 14; ++c) {
                const unsigned int bit = 1u << (13 - c);
                if (softmask & bit) {
                    const bool on = (rem & 1u) != 0u;
                    pr *= on ? pp[c] : qq[c];
                    if (on) code |= bit;
                    rem >>= 1;
                }
            }
            atomicAdd(hist + code, pr);
        }
    }

    // ---- phase 3: completion gate; last block finalizes (R8-proven) ----
    __threadfence();
    __syncthreads();
    __shared__ unsigned int slast;
    if (tid == 0) {
        const unsigned int prev = atomicAdd(counter, 1u);
        slast = (prev == (unsigned int)(gridDim.x - 1)) ? 1u : 0u;
    }
    __syncthreads();
    if (slast == 0u) return;

    __threadfence();
    __shared__ float sredf[256];

    float ce = 0.f;
#pragma unroll
    for (int rep = 0; rep < NB / 256; ++rep) {
        const float hv = atomicAdd(hist + rep * 256 + tid, 0.f);  // coherent load
        const float a = hv * (1.f / (float)NTOK);
        if (a > 0.f) ce -= a * logf(fmaxf(a, FEPS));
    }
    const float ps = pse_part[tid];
    const float cm = com_part[tid];

    sredf[tid] = ce; __syncthreads();
    for (int s = 128; s > 0; s >>= 1) { if (tid < s) sredf[tid] += sredf[tid + s]; __syncthreads(); }
    const float ce_sum = sredf[0]; __syncthreads();

    sredf[tid] = ps; __syncthreads();
    for (int s = 128; s > 0; s >>= 1) { if (tid < s) sredf[tid] += sredf[tid + s]; __syncthreads(); }
    const float ps_sum = sredf[0]; __syncthreads();

    sredf[tid] = cm; __syncthreads();
    for (int s = 128; s > 0; s >>= 1) { if (tid < s) sredf[tid] += sredf[tid + s]; __syncthreads(); }
    const float cm_sum = sredf[0];

    if (tid == 0) {
        const float per_sample = ps_sum * (1.f / (float)NTOK);
        const float commit = cm_sum * (1.f / ((float)NTOK * (float)CDIM));
        aux_out[0] = (per_sample - ce_sum) * 0.1f + commit;
    }
}

// ===========================================================================
// Fallback path (R5-proven) — used only if ws too small.
// ===========================================================================
__global__ __launch_bounds__(256) void k_partial(
    const float* __restrict__ x,
    const float* __restrict__ W_in,
    float* __restrict__ pw,
    float* __restrict__ hist)
{
    __shared__ float Wl[128][16];
    __shared__ float sred[4][64][15];

    const int tid = threadIdx.x;
    const int bid = blockIdx.x;

    if (bid < 64) hist[bid * 256 + tid] = 0.f;

    const int tile = bid >> 2;
    const int dgrp = bid & 3;
    const int d0 = dgrp * 128;

    for (int i = tid; i < 128 * CDIM; i += 256) {
        const int c = i >> 7;
        const int r = i & 127;
        Wl[r][c] = W_in[c * DIM + d0 + r];
    }
    __syncthreads();

    const int w = tid >> 6;
    const int lane = tid & 63;
    const int tl = lane & 15;
    const int dr = lane >> 4;

    const int tok0 = tile * 64 + tl * 4;
    const int b = tok0 >> 11;
    const int t = tok0 & (TT - 1);
    const int wd0 = w * 32;

    float acc[4][14];
#pragma unroll
    for (int j = 0; j < 4; ++j)
#pragma unroll
        for (int c = 0; c < 14; ++c) acc[j][c] = 0.f;

#pragma unroll
    for (int i = 0; i < 8; ++i) {
        const int r = wd0 + i * 4 + dr;
        const float4 xv = *(const float4*)(x + ((size_t)(b * DIM + d0 + r) * TT + t));
        const float4* wr = (const float4*)(&Wl[r][0]);
        const float4 w0 = wr[0];
        const float4 w1 = wr[1];
        const float4 w2 = wr[2];
        const float2 w3 = ((const float2*)wr)[6];
        const float xs[4] = {xv.x, xv.y, xv.z, xv.w};
#pragma unroll
        for (int j = 0; j < 4; ++j) {
            const float v = xs[j];
            acc[j][0]  = fmaf(v, w0.x, acc[j][0]);
            acc[j][1]  = fmaf(v, w0.y, acc[j][1]);
            acc[j][2]  = fmaf(v, w0.z, acc[j][2]);
            acc[j][3]  = fmaf(v, w0.w, acc[j][3]);
            acc[j][4]  = fmaf(v, w1.x, acc[j][4]);
            acc[j][5]  = fmaf(v, w1.y, acc[j][5]);
            acc[j][6]  = fmaf(v, w1.z, acc[j][6]);
            acc[j][7]  = fmaf(v, w1.w, acc[j][7]);
            acc[j][8]  = fmaf(v, w2.x, acc[j][8]);
            acc[j][9]  = fmaf(v, w2.y, acc[j][9]);
            acc[j][10] = fmaf(v, w2.z, acc[j][10]);
            acc[j][11] = fmaf(v, w2.w, acc[j][11]);
            acc[j][12] = fmaf(v, w3.x, acc[j][12]);
            acc[j][13] = fmaf(v, w3.y, acc[j][13]);
        }
    }

#pragma unroll
    for (int j = 0; j < 4; ++j)
#pragma unroll
        for (int c = 0; c < 14; ++c) {
            float v = acc[j][c];
            v += __shfl_xor(v, 16);
            v += __shfl_xor(v, 32);
            acc[j][c] = v;
        }

    if (dr == 0) {
#pragma unroll
        for (int j = 0; j < 4; ++j)
#pragma unroll
            for (int c = 0; c < 14; ++c)
                sred[w][tl * 4 + j][c] = acc[j][c];
    }
    __syncthreads();

    for (int p = tid; p < 64 * CDIM; p += 256) {
        const int c = p >> 6;
        const int tk = p & 63;
        const float s = sred[0][tk][c] + sred[1][tk][c] + sred[2][tk][c] + sred[3][tk][c];
        pw[((dgrp * CDIM + c) << 13) + tile * 64 + tk] = s;
    }
}

__global__ __launch_bounds__(256) void k_tail_w(
    const float* __restrict__ pw,
    const float* __restrict__ b_in,
    float* __restrict__ out_idx,
    float* __restrict__ hist,
    float* __restrict__ pse_part,
    float* __restrict__ commit_part)
{
    __shared__ float sps[4], scm[4];
    const int tid = threadIdx.x;
    const int w = tid >> 6;
    const int lane = tid & 63;
    const int tok = blockIdx.x * 4 + w;

    float h[14];
#pragma unroll
    for (int c = 0; c < 14; ++c) {
        float s = b_in[c];
#pragma unroll
        for (int g = 0; g < 4; ++g)
            s += pw[((g * CDIM + c) << 13) + tok];
        h[c] = s;
    }

    unsigned int idx = 0, base = 0, softmask = 0;
    float pse = 0.f, commit = 0.f;
    float pp[14], qq[14];
#pragma unroll
    for (int c = 0; c < 14; ++c) {
        const float hc = h[c];
        const unsigned int bit = 1u << (13 - c);
        const bool pos = hc > 0.f;
        if (pos) idx |= bit;
        const float sgn = pos ? 1.f : -1.f;
        const float dlt = hc - sgn;
        commit += dlt * dlt;
        const float pc = 1.f / (1.f + expf(-400.f * hc));
        const float qc = 1.f - pc;
        pse -= pc * logf(fmaxf(pc, FEPS)) + qc * logf(fmaxf(qc, FEPS));
        const bool hard1 = (qc <= PHARD);
        const bool hard0 = (pc <= PHARD);
        if (hard1) base |= bit;
        if (!hard1 && !hard0) softmask |= bit;
        pp[c] = pc;
        qq[c] = qc;
    }

    const unsigned int nsub = 1u << __popc(softmask);
    for (unsigned int m = lane; m < nsub; m += 64) {
        unsigned int rem = m, code = base;
        float pr = 1.f;
#pragma unroll
        for (int c = 0; c < 14; ++c) {
            const unsigned int bit = 1u << (13 - c);
            if (softmask & bit) {
                const bool on = (rem & 1u) != 0u;
                pr *= on ? pp[c] : qq[c];
                if (on) code |= bit;
                rem >>= 1;
            }
        }
        atomicAdd(hist + code, pr);
    }

    if (lane == 0) {
        out_idx[tok] = (float)idx;
        sps[w] = pse;
        scm[w] = commit;
    }
    __syncthreads();
    if (tid == 0) {
        pse_part[blockIdx.x]    = (sps[0] + sps[1]) + (sps[2] + sps[3]);
        commit_part[blockIdx.x] = (scm[0] + scm[1]) + (scm[2] + scm[3]);
    }
}

__global__ __launch_bounds__(256) void k_projfin(
    const float* __restrict__ idxf,
    const float* __restrict__ W_out,
    const float* __restrict__ b_out,
    float* __restrict__ out,
    const float* __restrict__ hist,
    const float* __restrict__ pse_part,
    const float* __restrict__ commit_part,
    float* __restrict__ aux_out,
    int nrep)
{
    const int tid = threadIdx.x;
    const int base = blockIdx.x * 1024;
    const int b = base >> 20;
    const int d = (base >> 11) & (DIM - 1);
    const int t = (base & (TT - 1)) + tid * 4;

    const float4 uf = *(const float4*)(idxf + b * TT + t);
    float w[14];
#pragma unroll
    for (int c = 0; c < 14; ++c) w[c] = W_out[d * 14 + c];
    const float bo = b_out[d];

    const float us[4] = {uf.x, uf.y, uf.z, uf.w};
    float os[4];
#pragma unroll
    for (int j = 0; j < 4; ++j) {
        const unsigned int u = (unsigned int)us[j];
        float s = bo;
#pragma unroll
        for (int c = 0; c < 14; ++c)
            s += (u & (1u << (13 - c))) ? w[c] : -w[c];
        os[j] = s;
    }
    float4 o; o.x = os[0]; o.y = os[1]; o.z = os[2]; o.w = os[3];
    *(float4*)(out + base + tid * 4) = o;

    if (blockIdx.x != 0) return;

    __shared__ float sred[256];
    float ce = 0.f;
#pragma unroll
    for (int rep = 0; rep < 16; ++rep) {
        const float4 hv = *(const float4*)(hist + (rep * 256 + tid) * 4);
        const float hs[4] = {hv.x, hv.y, hv.z, hv.w};
#pragma unroll
        for (int j = 0; j < 4; ++j) {
            const float a = hs[j] * (1.f / (float)NTOK);
            if (a > 0.f) ce -= a * logf(fmaxf(a, FEPS));
        }
    }
    float ps = 0.f, cm = 0.f;
    for (int r = 0; r < nrep; ++r) {
        ps += pse_part[r * 256 + tid];
        cm += commit_part[r * 256 + tid];
    }

    sred[tid] = ce; __syncthreads();
    for (int s = 128; s > 0; s >>= 1) { if (tid < s) sred[tid] += sred[tid + s]; __syncthreads(); }
    const float ce_sum = sred[0]; __syncthreads();

    sred[tid] = ps; __syncthreads();
    for (int s = 128; s > 0; s >>= 1) { if (tid < s) sred[tid] += sred[tid + s]; __syncthreads(); }
    const float ps_sum = sred[0]; __syncthreads();

    sred[tid] = cm; __syncthreads();
    for (int s = 128; s > 0; s >>= 1) { if (tid < s) sred[tid] += sred[tid + s]; __syncthreads(); }
    const float cm_sum = sred[0];

    if (tid == 0) {
        const float per_sample = ps_sum * (1.f / (float)NTOK);
        const float commit = cm_sum * (1.f / ((float)NTOK * (float)CDIM));
        aux_out[0] = (per_sample - ce_sum) * 0.1f + commit;
    }
}

extern "C" void kernel_launch(void* const* d_in, const int* in_sizes, int n_in,
                              void* d_out, int out_size, void* d_ws, size_t ws_size,
                              hipStream_t stream)
{
    (void)in_sizes; (void)n_in; (void)out_size;

    const float* x     = (const float*)d_in[0];
    const float* W_in  = (const float*)d_in[1];
    const float* b_in  = (const float*)d_in[2];
    const float* W_out = (const float*)d_in[3];
    const float* b_out = (const float*)d_in[4];

    float* out     = (float*)d_out;
    float* out_idx = out + OUT_ELEMS;
    float* out_aux = out + OUT_ELEMS + NTOK;

    char* ws = (char*)d_ws;

    if (ws_size >= (size_t)WS3_NEED) {
        float* pse_part    = (float*)(ws + WS3_PSE_OFF);
        float* com_part    = (float*)(ws + WS3_COM_OFF);
        unsigned int* cntr = (unsigned int*)(ws + WS3_CNTR_OFF);
        float* h_ws        = (float*)(ws + WS3_H_OFF);
        float* hist        = (float*)(ws + WS3_HIST_OFF);

        k_head2<<<dim3(256), dim3(512), 0, stream>>>(
            x, W_in, b_in, out_idx, h_ws, hist, cntr, pse_part, com_part);
        k_mega2<<<dim3(2048), dim3(256), 0, stream>>>(
            out_idx, W_out, b_out, out, h_ws, hist, cntr,
            pse_part, com_part, out_aux);
    } else {
        float* hist        = (float*)(ws + WS_HIST_OFF);
        float* pse_part    = (float*)(ws + WS_PSE_OFF);
        float* commit_part = (float*)(ws + WS_COM_OFF);
        float* pw          = (float*)(ws + WS_PW_OFF);

        k_partial<<<dim3(512), dim3(256), 0, stream>>>(x, W_in, pw, hist);
        k_tail_w<<<dim3(NTOK / 4), dim3(256), 0, stream>>>(
            pw, b_in, out_idx, hist, pse_part, commit_part);
        k_projfin<<<dim3(OUT_ELEMS / 1024), dim3(256), 0, stream>>>(
            out_idx, W_out, b_out, out, hist, pse_part, commit_part, out_aux, 8);
    }
}

// Round 13
// 33.780 us; speedup vs baseline: 5.7767x; 5.7767x over previous
//
#include <hip/hip_runtime.h>
#include <math.h>

#define BDIM 4
#define DIM 512
#define TT 2048
#define CDIM 14
#define NTOK (BDIM * TT)              // 8192 tokens
#define NB 16384                      // 2^14 codes
#define OUT_ELEMS (BDIM * DIM * TT)   // 4194304
#define FEPS 1e-20f
#define PHARD 1e-6f                   // soft-bit cutoff (aux err <1e-5 vs thr 327)

// ---- fast-path ws layout ----
#define WS4_PSE_OFF  0                // 256 f32
#define WS4_COM_OFF  1024             // 256 f32
#define WS4_HIST_OFF 4096             // 16384 f32 = 64 KB (16B aligned)
#define WS4_NEED     69632

// ---- fallback-path ws layout (R5-proven) ----
#define WS_HIST_OFF 0
#define WS_PSE_OFF  65536
#define WS_COM_OFF  73728
#define WS_PW_OFF   81920
#define WS_NEED (81920 + 4 * 14 * 8192 * 4)

// ===========================================================================
// Node 0: zero the histogram (own tiny kernel).
// ===========================================================================
__global__ __launch_bounds__(256) void k_zero(float* __restrict__ hist)
{
    hist[blockIdx.x * 256 + threadIdx.x] = 0.f;
}

// ===========================================================================
// Node 1: k_headA — GEMV + tail + hist atomics (R10-proven: 34.0us total,
// absmax 0.0). 256 blocks x 512 thr; block = 32 tokens x all 512 d.
// ===========================================================================
__global__ __launch_bounds__(512) void k_headA(
    const float* __restrict__ x,
    const float* __restrict__ W_in,
    const float* __restrict__ b_in,
    float* __restrict__ out_idx,
    float* __restrict__ hist,
    float* __restrict__ pse_part,
    float* __restrict__ com_part)
{
    __shared__ float Wl[DIM][16];       // 32 KB
    __shared__ float sred[8][32][15];   // 15 KB
    __shared__ float sps[8], scm[8];

    const int tid = threadIdx.x;
    const int bid = blockIdx.x;
    const int b = bid >> 6;             // 64 tiles per batch
    const int t0 = (bid & 63) * 32;

    for (int i = tid; i < DIM * CDIM; i += 512) {
        const int c = i >> 9;
        const int r = i & (DIM - 1);
        Wl[r][c] = W_in[c * DIM + r];
    }
    __syncthreads();

    const int w = tid >> 6;             // wave 0..7 -> d-rows [w*64, w*64+64)
    const int lane = tid & 63;
    const int tl = lane & 7;            // 8 t-lanes x float4 = 32 tokens
    const int dr = lane >> 3;           // 8 d-rows per instruction

    float acc[4][14];
#pragma unroll
    for (int j = 0; j < 4; ++j)
#pragma unroll
        for (int c = 0; c < 14; ++c) acc[j][c] = 0.f;

#pragma unroll
    for (int i = 0; i < 8; ++i) {
        const int r = w * 64 + i * 8 + dr;
        const float4 xv = *(const float4*)(x + (size_t)(b * DIM + r) * TT + t0 + tl * 4);
        const float4* wr = (const float4*)(&Wl[r][0]);
        const float4 w0 = wr[0];
        const float4 w1 = wr[1];
        const float4 w2 = wr[2];
        const float2 w3 = ((const float2*)wr)[6];
        const float xs[4] = {xv.x, xv.y, xv.z, xv.w};
#pragma unroll
        for (int j = 0; j < 4; ++j) {
            const float v = xs[j];
            acc[j][0]  = fmaf(v, w0.x, acc[j][0]);
            acc[j][1]  = fmaf(v, w0.y, acc[j][1]);
            acc[j][2]  = fmaf(v, w0.z, acc[j][2]);
            acc[j][3]  = fmaf(v, w0.w, acc[j][3]);
            acc[j][4]  = fmaf(v, w1.x, acc[j][4]);
            acc[j][5]  = fmaf(v, w1.y, acc[j][5]);
            acc[j][6]  = fmaf(v, w1.z, acc[j][6]);
            acc[j][7]  = fmaf(v, w1.w, acc[j][7]);
            acc[j][8]  = fmaf(v, w2.x, acc[j][8]);
            acc[j][9]  = fmaf(v, w2.y, acc[j][9]);
            acc[j][10] = fmaf(v, w2.z, acc[j][10]);
            acc[j][11] = fmaf(v, w2.w, acc[j][11]);
            acc[j][12] = fmaf(v, w3.x, acc[j][12]);
            acc[j][13] = fmaf(v, w3.y, acc[j][13]);
        }
    }

#pragma unroll
    for (int j = 0; j < 4; ++j)
#pragma unroll
        for (int c = 0; c < 14; ++c) {
            float v = acc[j][c];
            v += __shfl_xor(v, 8);
            v += __shfl_xor(v, 16);
            v += __shfl_xor(v, 32);
            acc[j][c] = v;
        }

    if (dr == 0) {
#pragma unroll
        for (int j = 0; j < 4; ++j)
#pragma unroll
            for (int c = 0; c < 14; ++c)
                sred[w][tl * 4 + j][c] = acc[j][c];
    }
    __syncthreads();

    // ---- tail: wave w handles tokens w*4..w*4+3; 16 lanes per token ----
    const int g = lane >> 4;
    const int sub = lane & 15;
    const int tk = w * 4 + g;
    const int tok = bid * 32 + tk;

    float h[14];
#pragma unroll
    for (int c = 0; c < 14; ++c) {
        float s = b_in[c];
#pragma unroll
        for (int wv = 0; wv < 8; ++wv) s += sred[wv][tk][c];
        h[c] = s;
    }

    unsigned int idx = 0, base = 0, softmask = 0;
    float pse = 0.f, commit = 0.f;
    float pp[14], qq[14];
#pragma unroll
    for (int c = 0; c < 14; ++c) {
        const float hc = h[c];
        const unsigned int bit = 1u << (13 - c);
        const bool pos = hc > 0.f;
        if (pos) idx |= bit;
        const float sgn = pos ? 1.f : -1.f;
        const float dlt = hc - sgn;
        commit += dlt * dlt;
        const float pc = 1.f / (1.f + expf(-400.f * hc));  // sigmoid(400h)
        const float qc = 1.f - pc;
        pse -= pc * logf(fmaxf(pc, FEPS)) + qc * logf(fmaxf(qc, FEPS));
        const bool hard1 = (qc <= PHARD);
        const bool hard0 = (pc <= PHARD);
        if (hard1) base |= bit;
        if (!hard1 && !hard0) softmask |= bit;
        pp[c] = pc;
        qq[c] = qc;
    }

    const unsigned int nsub = 1u << __popc(softmask);
    for (unsigned int m = sub; m < nsub; m += 16) {
        unsigned int rem = m, code = base;
        float pr = 1.f;
#pragma unroll
        for (int c = 0; c < 14; ++c) {
            const unsigned int bit = 1u << (13 - c);
            if (softmask & bit) {
                const bool on = (rem & 1u) != 0u;
                pr *= on ? pp[c] : qq[c];
                if (on) code |= bit;
                rem >>= 1;
            }
        }
        atomicAdd(hist + code, pr);
    }

    if (sub == 0) {
        out_idx[tok] = (float)idx;
    }

    float pv = (sub == 0) ? pse : 0.f;
    float cv = (sub == 0) ? commit : 0.f;
#pragma unroll
    for (int o = 1; o < 64; o <<= 1) {
        pv += __shfl_xor(pv, o);
        cv += __shfl_xor(cv, o);
    }
    if (lane == 0) { sps[w] = pv; scm[w] = cv; }
    __syncthreads();
    if (tid == 0) {
        float a = 0.f, bb = 0.f;
#pragma unroll
        for (int i = 0; i < 8; ++i) { a += sps[i]; bb += scm[i]; }
        pse_part[bid] = a;
        com_part[bid] = bb;
    }
}

// ===========================================================================
// Node 2: k_projfin — coalesced proj_out (4096 blocks x 256) + block-0
// dense-hist finalize. nrep = number of 256-entry partial groups (R9 bug fix:
// fast path writes 256 partials -> nrep=1; fallback 2048 -> nrep=8).
// ===========================================================================
__global__ __launch_bounds__(256) void k_projfin(
    const float* __restrict__ idxf,
    const float* __restrict__ W_out,
    const float* __restrict__ b_out,
    float* __restrict__ out,
    const float* __restrict__ hist,
    const float* __restrict__ pse_part,
    const float* __restrict__ commit_part,
    float* __restrict__ aux_out,
    int nrep)
{
    const int tid = threadIdx.x;
    const int base = blockIdx.x * 1024;
    const int b = base >> 20;
    const int d = (base >> 11) & (DIM - 1);
    const int t = (base & (TT - 1)) + tid * 4;

    const float4 uf = *(const float4*)(idxf + b * TT + t);
    float w[14];
#pragma unroll
    for (int c = 0; c < 14; ++c) w[c] = W_out[d * 14 + c];
    const float bo = b_out[d];

    const float us[4] = {uf.x, uf.y, uf.z, uf.w};
    float os[4];
#pragma unroll
    for (int j = 0; j < 4; ++j) {
        const unsigned int u = (unsigned int)us[j];
        float s = bo;
#pragma unroll
        for (int c = 0; c < 14; ++c)
            s += (u & (1u << (13 - c))) ? w[c] : -w[c];
        os[j] = s;
    }
    float4 o; o.x = os[0]; o.y = os[1]; o.z = os[2]; o.w = os[3];
    *(float4*)(out + base + tid * 4) = o;

    if (blockIdx.x != 0) return;

    __shared__ float sred[256];
    float ce = 0.f;
#pragma unroll
    for (int rep = 0; rep < 16; ++rep) {
        const float4 hv = *(const float4*)(hist + (rep * 256 + tid) * 4);
        const float hs[4] = {hv.x, hv.y, hv.z, hv.w};
#pragma unroll
        for (int j = 0; j < 4; ++j) {
            const float a = hs[j] * (1.f / (float)NTOK);
            if (a > 0.f) ce -= a * logf(fmaxf(a, FEPS));
        }
    }
    float ps = 0.f, cm = 0.f;
    for (int r = 0; r < nrep; ++r) {
        ps += pse_part[r * 256 + tid];
        cm += commit_part[r * 256 + tid];
    }

    sred[tid] = ce; __syncthreads();
    for (int s = 128; s > 0; s >>= 1) { if (tid < s) sred[tid] += sred[tid + s]; __syncthreads(); }
    const float ce_sum = sred[0]; __syncthreads();

    sred[tid] = ps; __syncthreads();
    for (int s = 128; s > 0; s >>= 1) { if (tid < s) sred[tid] += sred[tid + s]; __syncthreads(); }
    const float ps_sum = sred[0]; __syncthreads();

    sred[tid] = cm; __syncthreads();
    for (int s = 128; s > 0; s >>= 1) { if (tid < s) sred[tid] += sred[tid + s]; __syncthreads(); }
    const float cm_sum = sred[0];

    if (tid == 0) {
        const float per_sample = ps_sum * (1.f / (float)NTOK);
        const float commit = cm_sum * (1.f / ((float)NTOK * (float)CDIM));
        aux_out[0] = (per_sample - ce_sum) * 0.1f + commit;
    }
}

// ===========================================================================
// Fallback path (R5-proven 3-kernel pipeline) — used only if ws too small.
// ===========================================================================
__global__ __launch_bounds__(256) void k_partial(
    const float* __restrict__ x,
    const float* __restrict__ W_in,
    float* __restrict__ pw,
    float* __restrict__ hist)
{
    __shared__ float Wl[128][16];
    __shared__ float sred[4][64][15];

    const int tid = threadIdx.x;
    const int bid = blockIdx.x;

    if (bid < 64) hist[bid * 256 + tid] = 0.f;

    const int tile = bid >> 2;
    const int dgrp = bid & 3;
    const int d0 = dgrp * 128;

    for (int i = tid; i < 128 * CDIM; i += 256) {
        const int c = i >> 7;
        const int r = i & 127;
        Wl[r][c] = W_in[c * DIM + d0 + r];
    }
    __syncthreads();

    const int w = tid >> 6;
    const int lane = tid & 63;
    const int tl = lane & 15;
    const int dr = lane >> 4;

    const int tok0 = tile * 64 + tl * 4;
    const int b = tok0 >> 11;
    const int t = tok0 & (TT - 1);
    const int wd0 = w * 32;

    float acc[4][14];
#pragma unroll
    for (int j = 0; j < 4; ++j)
#pragma unroll
        for (int c = 0; c < 14; ++c) acc[j][c] = 0.f;

#pragma unroll
    for (int i = 0; i < 8; ++i) {
        const int r = wd0 + i * 4 + dr;
        const float4 xv = *(const float4*)(x + ((size_t)(b * DIM + d0 + r) * TT + t));
        const float4* wr = (const float4*)(&Wl[r][0]);
        const float4 w0 = wr[0];
        const float4 w1 = wr[1];
        const float4 w2 = wr[2];
        const float2 w3 = ((const float2*)wr)[6];
        const float xs[4] = {xv.x, xv.y, xv.z, xv.w};
#pragma unroll
        for (int j = 0; j < 4; ++j) {
            const float v = xs[j];
            acc[j][0]  = fmaf(v, w0.x, acc[j][0]);
            acc[j][1]  = fmaf(v, w0.y, acc[j][1]);
            acc[j][2]  = fmaf(v, w0.z, acc[j][2]);
            acc[j][3]  = fmaf(v, w0.w, acc[j][3]);
            acc[j][4]  = fmaf(v, w1.x, acc[j][4]);
            acc[j][5]  = fmaf(v, w1.y, acc[j][5]);
            acc[j][6]  = fmaf(v, w1.z, acc[j][6]);
            acc[j][7]  = fmaf(v, w1.w, acc[j][7]);
            acc[j][8]  = fmaf(v, w2.x, acc[j][8]);
            acc[j][9]  = fmaf(v, w2.y, acc[j][9]);
            acc[j][10] = fmaf(v, w2.z, acc[j][10]);
            acc[j][11] = fmaf(v, w2.w, acc[j][11]);
            acc[j][12] = fmaf(v, w3.x, acc[j][12]);
            acc[j][13] = fmaf(v, w3.y, acc[j][13]);
        }
    }

#pragma unroll
    for (int j = 0; j < 4; ++j)
#pragma unroll
        for (int c = 0; c < 14; ++c) {
            float v = acc[j][c];
            v += __shfl_xor(v, 16);
            v += __shfl_xor(v, 32);
            acc[j][c] = v;
        }

    if (dr == 0) {
#pragma unroll
        for (int j = 0; j < 4; ++j)
#pragma unroll
            for (int c = 0; c < 14; ++c)
                sred[w][tl * 4 + j][c] = acc[j][c];
    }
    __syncthreads();

    for (int p = tid; p < 64 * CDIM; p += 256) {
        const int c = p >> 6;
        const int tk = p & 63;
        const float s = sred[0][tk][c] + sred[1][tk][c] + sred[2][tk][c] + sred[3][tk][c];
        pw[((dgrp * CDIM + c) << 13) + tile * 64 + tk] = s;
    }
}

__global__ __launch_bounds__(256) void k_tail_w(
    const float* __restrict__ pw,
    const float* __restrict__ b_in,
    float* __restrict__ out_idx,
    float* __restrict__ hist,
    float* __restrict__ pse_part,
    float* __restrict__ commit_part)
{
    __shared__ float sps[4], scm[4];
    const int tid = threadIdx.x;
    const int w = tid >> 6;
    const int lane = tid & 63;
    const int tok = blockIdx.x * 4 + w;

    float h[14];
#pragma unroll
    for (int c = 0; c < 14; ++c) {
        float s = b_in[c];
#pragma unroll
        for (int g = 0; g < 4; ++g)
            s += pw[((g * CDIM + c) << 13) + tok];
        h[c] = s;
    }

    unsigned int idx = 0, base = 0, softmask = 0;
    float pse = 0.f, commit = 0.f;
    float pp[14], qq[14];
#pragma unroll
    for (int c = 0; c < 14; ++c) {
        const float hc = h[c];
        const unsigned int bit = 1u << (13 - c);
        const bool pos = hc > 0.f;
        if (pos) idx |= bit;
        const float sgn = pos ? 1.f : -1.f;
        const float dlt = hc - sgn;
        commit += dlt * dlt;
        const float pc = 1.f / (1.f + expf(-400.f * hc));
        const float qc = 1.f - pc;
        pse -= pc * logf(fmaxf(pc, FEPS)) + qc * logf(fmaxf(qc, FEPS));
        const bool hard1 = (qc <= PHARD);
        const bool hard0 = (pc <= PHARD);
        if (hard1) base |= bit;
        if (!hard1 && !hard0) softmask |= bit;
        pp[c] = pc;
        qq[c] = qc;
    }

    const unsigned int nsub = 1u << __popc(softmask);
    for (unsigned int m = lane; m < nsub; m += 64) {
        unsigned int rem = m, code = base;
        float pr = 1.f;
#pragma unroll
        for (int c = 0; c < 14; ++c) {
            const unsigned int bit = 1u << (13 - c);
            if (softmask & bit) {
                const bool on = (rem & 1u) != 0u;
                pr *= on ? pp[c] : qq[c];
                if (on) code |= bit;
                rem >>= 1;
            }
        }
        atomicAdd(hist + code, pr);
    }

    if (lane == 0) {
        out_idx[tok] = (float)idx;
        sps[w] = pse;
        scm[w] = commit;
    }
    __syncthreads();
    if (tid == 0) {
        pse_part[blockIdx.x]    = (sps[0] + sps[1]) + (sps[2] + sps[3]);
        commit_part[blockIdx.x] = (scm[0] + scm[1]) + (scm[2] + scm[3]);
    }
}

extern "C" void kernel_launch(void* const* d_in, const int* in_sizes, int n_in,
                              void* d_out, int out_size, void* d_ws, size_t ws_size,
                              hipStream_t stream)
{
    (void)in_sizes; (void)n_in; (void)out_size;

    const float* x     = (const float*)d_in[0];
    const float* W_in  = (const float*)d_in[1];
    const float* b_in  = (const float*)d_in[2];
    const float* W_out = (const float*)d_in[3];
    const float* b_out = (const float*)d_in[4];

    float* out     = (float*)d_out;
    float* out_idx = out + OUT_ELEMS;
    float* out_aux = out + OUT_ELEMS + NTOK;

    char* ws = (char*)d_ws;

    if (ws_size >= (size_t)WS4_NEED) {
        float* pse_part = (float*)(ws + WS4_PSE_OFF);
        float* com_part = (float*)(ws + WS4_COM_OFF);
        float* hist     = (float*)(ws + WS4_HIST_OFF);

        k_zero<<<dim3(NB / 256), dim3(256), 0, stream>>>(hist);
        k_headA<<<dim3(256), dim3(512), 0, stream>>>(
            x, W_in, b_in, out_idx, hist, pse_part, com_part);
        k_projfin<<<dim3(OUT_ELEMS / 1024), dim3(256), 0, stream>>>(
            out_idx, W_out, b_out, out, hist, pse_part, com_part, out_aux, 1);
    } else {
        float* hist        = (float*)(ws + WS_HIST_OFF);
        float* pse_part    = (float*)(ws + WS_PSE_OFF);
        float* commit_part = (float*)(ws + WS_COM_OFF);
        float* pw          = (float*)(ws + WS_PW_OFF);

        k_partial<<<dim3(512), dim3(256), 0, stream>>>(x, W_in, pw, hist);
        k_tail_w<<<dim3(NTOK / 4), dim3(256), 0, stream>>>(
            pw, b_in, out_idx, hist, pse_part, commit_part);
        k_projfin<<<dim3(OUT_ELEMS / 1024), dim3(256), 0, stream>>>(
            out_idx, W_out, b_out, out, hist, pse_part, commit_part, out_aux, 8);
    }
}